// Round 2
// baseline (1943.776 us; speedup 1.0000x reference)
//
#include <hip/hip_runtime.h>

#define NNODE 100000
#define NEDGE 1600000
#define DFEAT 64
#define DEPTH 10
#define STRIDE ((DEPTH + 1) * DFEAT)  // 704 floats per node in output

// ---------- CSR build ----------

__global__ void hist_kernel(const int* __restrict__ ei, int* __restrict__ counts, int E) {
    int e = blockIdx.x * blockDim.x + threadIdx.x;
    if (e < E) atomicAdd(&counts[ei[e]], 1);
}

__global__ void dinv_kernel(const int* __restrict__ counts, float* __restrict__ dinv, int n) {
    int i = blockIdx.x * blockDim.x + threadIdx.x;
    if (i < n) {
        float d = (float)counts[i];
        if (d < 0.5f) d += 1.0f;  // reference: deg<0.5 -> deg+1
        dinv[i] = rsqrtf(d);
    }
}

// Single-block exclusive scan over counts -> rowptr; also seed woff = rowptr.
__global__ void scan_kernel(const int* __restrict__ counts, int* __restrict__ rowptr,
                            int* __restrict__ woff, int n) {
    __shared__ int sums[256];
    int t = threadIdx.x;
    int chunk = (n + 255) / 256;
    int lo = t * chunk;
    int hi = min(n, lo + chunk);
    int s = 0;
    for (int i = lo; i < hi; ++i) s += counts[i];
    sums[t] = s;
    __syncthreads();
    // in-place Hillis-Steele inclusive scan
    for (int off = 1; off < 256; off <<= 1) {
        int o = (t >= off) ? sums[t - off] : 0;
        __syncthreads();
        sums[t] += o;
        __syncthreads();
    }
    int run = sums[t] - s;  // exclusive prefix
    for (int i = lo; i < hi; ++i) {
        rowptr[i] = run;
        woff[i] = run;
        run += counts[i];
    }
    if (hi == n) rowptr[n] = run;
}

__global__ void scatter_kernel(const int* __restrict__ ei, const float* __restrict__ ea,
                               const float* __restrict__ dinv, int* __restrict__ woff,
                               int* __restrict__ ccol, float* __restrict__ cval, int E) {
    int e = blockIdx.x * blockDim.x + threadIdx.x;
    if (e >= E) return;
    int r = ei[e];
    int c = ei[E + e];
    int pos = atomicAdd(&woff[r], 1);
    ccol[pos] = c;
    cval[pos] = dinv[r] * ea[e] * dinv[c];
}

// ---------- scalar recurrence coefficients ----------
// out_L = cA * spmm(x_{L-1}) + cB * x_{L-1} + cC * x_{L-2}
__global__ void coef_kernel(const float* __restrict__ alpha_params, float* __restrict__ coefs) {
    if (threadIdx.x != 0 || blockIdx.x != 0) return;
    const float a = 1.0f, b = 1.0f, l = -1.0f, r = 1.0f, basealpha = 1.0f;
    float alphas[DEPTH + 1];
    for (int i = 0; i <= DEPTH; ++i) alphas[i] = basealpha * tanhf(alpha_params[i]);
    // L = 1
    float coef1 = (a - b) * 0.5f - (a + b + 2.0f) * 0.5f * (l + r) / (r - l);
    float coef2 = (a + b + 2.0f) / (r - l);
    coefs[3 * 1 + 0] = alphas[0] * coef2;
    coefs[3 * 1 + 1] = alphas[0] * coef1;
    coefs[3 * 1 + 2] = 0.0f;
    for (int L = 2; L <= DEPTH; ++L) {
        float Lf = (float)L;
        float coef_l = 2.0f * Lf * (Lf + a + b) * (2.0f * Lf - 2.0f + a + b);
        float coef_lm1_1 = (2.0f * Lf + a + b - 1.0f) * (2.0f * Lf + a + b) * (2.0f * Lf + a + b - 2.0f);
        float coef_lm1_2 = (2.0f * Lf + a + b - 1.0f) * (a * a - b * b);
        float coef_lm2 = 2.0f * (Lf - 1.0f + a) * (Lf - 1.0f + b) * (2.0f * Lf + a + b);
        float tmp1 = alphas[L - 1] * (coef_lm1_1 / coef_l);
        float tmp2 = alphas[L - 1] * (coef_lm1_2 / coef_l);
        float tmp3 = alphas[L - 1] * alphas[L - 2] * (coef_lm2 / coef_l);
        float tmp1_2 = tmp1 * (2.0f / (r - l));
        float tmp2_2 = tmp1 * ((r + l) / (r - l)) + tmp2;
        coefs[3 * L + 0] = tmp1_2;
        coefs[3 * L + 1] = -tmp2_2;
        coefs[3 * L + 2] = -tmp3;
    }
}

// ---------- xs[0] = x into out[:, 0, :] ----------
__global__ void copyx_kernel(const float* __restrict__ x, float* __restrict__ out, int n) {
    int i = blockIdx.x * blockDim.x + threadIdx.x;
    if (i >= n * DFEAT) return;
    int node = i >> 6;
    int lane = i & 63;
    out[(size_t)node * STRIDE + lane] = x[i];
}

// ---------- fused spmm + recurrence, one wave per node, one lane per feature ----------
__global__ void spmm_kernel(const int* __restrict__ rowptr, const int* __restrict__ ccol,
                            const float* __restrict__ cval, const float* __restrict__ coefs,
                            float* __restrict__ out, int n, int L) {
    int gid = blockIdx.x * blockDim.x + threadIdx.x;
    int node = gid >> 6;
    int lane = gid & 63;
    if (node >= n) return;
    int s = rowptr[node];
    int e_end = rowptr[node + 1];
    const float* prev = out + (size_t)(L - 1) * DFEAT;  // xs[L-1] slice, indexed col*STRIDE + lane
    float acc = 0.0f;
    for (int e = s; e < e_end; ++e) {
        int c = ccol[e];
        float v = cval[e];
        acc += v * prev[(size_t)c * STRIDE + lane];
    }
    float cA = coefs[3 * L + 0];
    float cB = coefs[3 * L + 1];
    float cC = coefs[3 * L + 2];
    size_t base = (size_t)node * STRIDE;
    float p1 = out[base + (size_t)(L - 1) * DFEAT + lane];
    float p2 = (L >= 2) ? out[base + (size_t)(L - 2) * DFEAT + lane] : 0.0f;
    out[base + (size_t)L * DFEAT + lane] = cA * acc + cB * p1 + cC * p2;
}

extern "C" void kernel_launch(void* const* d_in, const int* in_sizes, int n_in,
                              void* d_out, int out_size, void* d_ws, size_t ws_size,
                              hipStream_t stream) {
    const float* x = (const float*)d_in[0];
    const float* ea = (const float*)d_in[1];
    const float* alpha = (const float*)d_in[2];
    const int* ei = (const int*)d_in[3];  // harness passes integer inputs as int32
    float* out = (float*)d_out;
    int n = in_sizes[0] / DFEAT;  // 100000
    int E = in_sizes[1];          // 1600000

    char* ws = (char*)d_ws;
    size_t off = 0;
    auto alloc = [&](size_t bytes) -> void* {
        void* p = ws + off;
        off += (bytes + 255) & ~(size_t)255;
        return p;
    };
    int* counts = (int*)alloc((size_t)n * 4);
    int* rowptr = (int*)alloc((size_t)(n + 1) * 4);
    int* woff = (int*)alloc((size_t)n * 4);
    float* dinv = (float*)alloc((size_t)n * 4);
    int* ccol = (int*)alloc((size_t)E * 4);
    float* cval = (float*)alloc((size_t)E * 4);
    float* coefs = (float*)alloc(3 * (DEPTH + 1) * 4);

    hipMemsetAsync(counts, 0, (size_t)n * 4, stream);
    hist_kernel<<<(E + 255) / 256, 256, 0, stream>>>(ei, counts, E);
    dinv_kernel<<<(n + 255) / 256, 256, 0, stream>>>(counts, dinv, n);
    scan_kernel<<<1, 256, 0, stream>>>(counts, rowptr, woff, n);
    scatter_kernel<<<(E + 255) / 256, 256, 0, stream>>>(ei, ea, dinv, woff, ccol, cval, E);
    coef_kernel<<<1, 64, 0, stream>>>(alpha, coefs);
    copyx_kernel<<<(n * DFEAT + 255) / 256, 256, 0, stream>>>(x, out, n);

    int spmm_blocks = (int)(((size_t)n * 64 + 255) / 256);
    for (int L = 1; L <= DEPTH; ++L) {
        spmm_kernel<<<spmm_blocks, 256, 0, stream>>>(rowptr, ccol, cval, coefs, out, n, L);
    }
}

// Round 3
// 946.234 us; speedup vs baseline: 2.0542x; 2.0542x over previous
//
#include <hip/hip_runtime.h>

#define NNODE 100000
#define NEDGE 1600000
#define DFEAT 64
#define DEPTH 10
#define STRIDE ((DEPTH + 1) * DFEAT)  // 704 floats per node in output
#define SCAN_BLK 256

// ---------- CSR build ----------

__global__ void hist_kernel(const int* __restrict__ ei, int* __restrict__ counts, int E) {
    int e = blockIdx.x * blockDim.x + threadIdx.x;
    if (e < E) atomicAdd(&counts[ei[e]], 1);
}

__global__ void dinv_kernel(const int* __restrict__ counts, float* __restrict__ dinv, int n) {
    int i = blockIdx.x * blockDim.x + threadIdx.x;
    if (i < n) {
        float d = (float)counts[i];
        if (d < 0.5f) d += 1.0f;  // reference: deg<0.5 -> deg+1
        dinv[i] = rsqrtf(d);
    }
}

// Hierarchical scan: (1) per-block sums, (2) scan block sums (1 block), (3) per-block scan + offset.
__global__ void scan1_kernel(const int* __restrict__ counts, int* __restrict__ blocksums, int n) {
    __shared__ int sh[SCAN_BLK];
    int t = threadIdx.x;
    int i = blockIdx.x * SCAN_BLK + t;
    sh[t] = (i < n) ? counts[i] : 0;
    __syncthreads();
    for (int off = SCAN_BLK / 2; off > 0; off >>= 1) {
        if (t < off) sh[t] += sh[t + off];
        __syncthreads();
    }
    if (t == 0) blocksums[blockIdx.x] = sh[0];
}

__global__ void scan2_kernel(const int* __restrict__ blocksums, int* __restrict__ blockoffs,
                             int* __restrict__ rowptr, int nb, int n) {
    __shared__ int sh[512];
    int t = threadIdx.x;
    int v = (t < nb) ? blocksums[t] : 0;
    sh[t] = v;
    __syncthreads();
    for (int off = 1; off < 512; off <<= 1) {
        int o = (t >= off) ? sh[t - off] : 0;
        __syncthreads();
        sh[t] += o;
        __syncthreads();
    }
    if (t < nb) blockoffs[t] = sh[t] - v;  // exclusive
    if (t == nb - 1) rowptr[n] = sh[t];    // total
}

__global__ void scan3_kernel(const int* __restrict__ counts, const int* __restrict__ blockoffs,
                             int* __restrict__ rowptr, int* __restrict__ woff, int n) {
    __shared__ int sh[SCAN_BLK];
    int t = threadIdx.x;
    int i = blockIdx.x * SCAN_BLK + t;
    int v = (i < n) ? counts[i] : 0;
    sh[t] = v;
    __syncthreads();
    for (int off = 1; off < SCAN_BLK; off <<= 1) {
        int o = (t >= off) ? sh[t - off] : 0;
        __syncthreads();
        sh[t] += o;
        __syncthreads();
    }
    if (i < n) {
        int excl = sh[t] - v + blockoffs[blockIdx.x];
        rowptr[i] = excl;
        woff[i] = excl;
    }
}

__global__ void scatter_kernel(const int* __restrict__ ei, const float* __restrict__ ea,
                               const float* __restrict__ dinv, int* __restrict__ woff,
                               int* __restrict__ ccol, float* __restrict__ cval, int E) {
    int e = blockIdx.x * blockDim.x + threadIdx.x;
    if (e >= E) return;
    int r = ei[e];
    int c = ei[E + e];
    int pos = atomicAdd(&woff[r], 1);
    ccol[pos] = c;
    cval[pos] = dinv[r] * ea[e] * dinv[c];
}

// ---------- scalar recurrence coefficients ----------
__global__ void coef_kernel(const float* __restrict__ alpha_params, float* __restrict__ coefs) {
    if (threadIdx.x != 0 || blockIdx.x != 0) return;
    const float a = 1.0f, b = 1.0f, l = -1.0f, r = 1.0f, basealpha = 1.0f;
    float alphas[DEPTH + 1];
    for (int i = 0; i <= DEPTH; ++i) alphas[i] = basealpha * tanhf(alpha_params[i]);
    float coef1 = (a - b) * 0.5f - (a + b + 2.0f) * 0.5f * (l + r) / (r - l);
    float coef2 = (a + b + 2.0f) / (r - l);
    coefs[3 * 1 + 0] = alphas[0] * coef2;
    coefs[3 * 1 + 1] = alphas[0] * coef1;
    coefs[3 * 1 + 2] = 0.0f;
    for (int L = 2; L <= DEPTH; ++L) {
        float Lf = (float)L;
        float coef_l = 2.0f * Lf * (Lf + a + b) * (2.0f * Lf - 2.0f + a + b);
        float coef_lm1_1 = (2.0f * Lf + a + b - 1.0f) * (2.0f * Lf + a + b) * (2.0f * Lf + a + b - 2.0f);
        float coef_lm1_2 = (2.0f * Lf + a + b - 1.0f) * (a * a - b * b);
        float coef_lm2 = 2.0f * (Lf - 1.0f + a) * (Lf - 1.0f + b) * (2.0f * Lf + a + b);
        float tmp1 = alphas[L - 1] * (coef_lm1_1 / coef_l);
        float tmp2 = alphas[L - 1] * (coef_lm1_2 / coef_l);
        float tmp3 = alphas[L - 1] * alphas[L - 2] * (coef_lm2 / coef_l);
        float tmp1_2 = tmp1 * (2.0f / (r - l));
        float tmp2_2 = tmp1 * ((r + l) / (r - l)) + tmp2;
        coefs[3 * L + 0] = tmp1_2;
        coefs[3 * L + 1] = -tmp2_2;
        coefs[3 * L + 2] = -tmp3;
    }
}

// ---------- xs[0] = x into out[:, 0, :] ----------
__global__ void copyx_kernel(const float* __restrict__ x, float* __restrict__ out, int n) {
    int i = blockIdx.x * blockDim.x + threadIdx.x;
    if (i >= n * DFEAT) return;
    int node = i >> 6;
    int lane = i & 63;
    out[(size_t)node * STRIDE + lane] = x[i];
}

// ---------- fused spmm + recurrence, one wave per node, one lane per feature ----------
// Edge loop unrolled 4x with independent accumulators for memory-level parallelism.
__global__ void spmm_kernel(const int* __restrict__ rowptr, const int* __restrict__ ccol,
                            const float* __restrict__ cval, const float* __restrict__ coefs,
                            float* __restrict__ out, int n, int L) {
    int gid = blockIdx.x * blockDim.x + threadIdx.x;
    int node = gid >> 6;
    int lane = gid & 63;
    if (node >= n) return;
    int s = rowptr[node];
    int e_end = rowptr[node + 1];
    const float* prev = out + (size_t)(L - 1) * DFEAT;  // xs[L-1] slice: col*STRIDE + lane
    float acc0 = 0.0f, acc1 = 0.0f, acc2 = 0.0f, acc3 = 0.0f;
    int e = s;
    for (; e + 4 <= e_end; e += 4) {
        int c0 = ccol[e], c1 = ccol[e + 1], c2 = ccol[e + 2], c3 = ccol[e + 3];
        float v0 = cval[e], v1 = cval[e + 1], v2 = cval[e + 2], v3 = cval[e + 3];
        acc0 += v0 * prev[(size_t)c0 * STRIDE + lane];
        acc1 += v1 * prev[(size_t)c1 * STRIDE + lane];
        acc2 += v2 * prev[(size_t)c2 * STRIDE + lane];
        acc3 += v3 * prev[(size_t)c3 * STRIDE + lane];
    }
    for (; e < e_end; ++e) {
        acc0 += cval[e] * prev[(size_t)ccol[e] * STRIDE + lane];
    }
    float acc = (acc0 + acc1) + (acc2 + acc3);
    float cA = coefs[3 * L + 0];
    float cB = coefs[3 * L + 1];
    float cC = coefs[3 * L + 2];
    size_t base = (size_t)node * STRIDE;
    float p1 = out[base + (size_t)(L - 1) * DFEAT + lane];
    float p2 = (L >= 2) ? out[base + (size_t)(L - 2) * DFEAT + lane] : 0.0f;
    out[base + (size_t)L * DFEAT + lane] = cA * acc + cB * p1 + cC * p2;
}

extern "C" void kernel_launch(void* const* d_in, const int* in_sizes, int n_in,
                              void* d_out, int out_size, void* d_ws, size_t ws_size,
                              hipStream_t stream) {
    const float* x = (const float*)d_in[0];
    const float* ea = (const float*)d_in[1];
    const float* alpha = (const float*)d_in[2];
    const int* ei = (const int*)d_in[3];
    float* out = (float*)d_out;
    int n = in_sizes[0] / DFEAT;  // 100000
    int E = in_sizes[1];          // 1600000
    int nb = (n + SCAN_BLK - 1) / SCAN_BLK;  // 391

    char* ws = (char*)d_ws;
    size_t off = 0;
    auto alloc = [&](size_t bytes) -> void* {
        void* p = ws + off;
        off += (bytes + 255) & ~(size_t)255;
        return p;
    };
    int* counts = (int*)alloc((size_t)n * 4);
    int* rowptr = (int*)alloc((size_t)(n + 1) * 4);
    int* woff = (int*)alloc((size_t)n * 4);
    float* dinv = (float*)alloc((size_t)n * 4);
    int* ccol = (int*)alloc((size_t)E * 4);
    float* cval = (float*)alloc((size_t)E * 4);
    float* coefs = (float*)alloc(3 * (DEPTH + 1) * 4);
    int* blocksums = (int*)alloc((size_t)nb * 4);
    int* blockoffs = (int*)alloc((size_t)nb * 4);

    hipMemsetAsync(counts, 0, (size_t)n * 4, stream);
    hist_kernel<<<(E + 255) / 256, 256, 0, stream>>>(ei, counts, E);
    dinv_kernel<<<nb, 256, 0, stream>>>(counts, dinv, n);
    scan1_kernel<<<nb, SCAN_BLK, 0, stream>>>(counts, blocksums, n);
    scan2_kernel<<<1, 512, 0, stream>>>(blocksums, blockoffs, rowptr, nb, n);
    scan3_kernel<<<nb, SCAN_BLK, 0, stream>>>(counts, blockoffs, rowptr, woff, n);
    scatter_kernel<<<(E + 255) / 256, 256, 0, stream>>>(ei, ea, dinv, woff, ccol, cval, E);
    coef_kernel<<<1, 64, 0, stream>>>(alpha, coefs);
    copyx_kernel<<<(n * DFEAT + 255) / 256, 256, 0, stream>>>(x, out, n);

    int spmm_blocks = (int)(((size_t)n * 64 + 255) / 256);
    for (int L = 1; L <= DEPTH; ++L) {
        spmm_kernel<<<spmm_blocks, 256, 0, stream>>>(rowptr, ccol, cval, coefs, out, n, L);
    }
}

// Round 4
// 887.522 us; speedup vs baseline: 2.1901x; 1.0662x over previous
//
#include <hip/hip_runtime.h>

#define NNODE 100000
#define NEDGE 1600000
#define DFEAT 64
#define DEPTH 10
#define STRIDE ((DEPTH + 1) * DFEAT)  // 704 floats per node in output
#define SCAN_BLK 256

// ---------- CSR build ----------

__global__ void hist_kernel(const int* __restrict__ ei, int* __restrict__ counts, int E) {
    int e = blockIdx.x * blockDim.x + threadIdx.x;
    if (e < E) atomicAdd(&counts[ei[e]], 1);
}

__global__ void dinv_kernel(const int* __restrict__ counts, float* __restrict__ dinv, int n) {
    int i = blockIdx.x * blockDim.x + threadIdx.x;
    if (i < n) {
        float d = (float)counts[i];
        if (d < 0.5f) d += 1.0f;  // reference: deg<0.5 -> deg+1
        dinv[i] = rsqrtf(d);
    }
}

// Hierarchical scan: (1) per-block sums, (2) scan block sums (1 block), (3) per-block scan + offset.
__global__ void scan1_kernel(const int* __restrict__ counts, int* __restrict__ blocksums, int n) {
    __shared__ int sh[SCAN_BLK];
    int t = threadIdx.x;
    int i = blockIdx.x * SCAN_BLK + t;
    sh[t] = (i < n) ? counts[i] : 0;
    __syncthreads();
    for (int off = SCAN_BLK / 2; off > 0; off >>= 1) {
        if (t < off) sh[t] += sh[t + off];
        __syncthreads();
    }
    if (t == 0) blocksums[blockIdx.x] = sh[0];
}

__global__ void scan2_kernel(const int* __restrict__ blocksums, int* __restrict__ blockoffs,
                             int* __restrict__ rowptr, int nb, int n) {
    __shared__ int sh[512];
    int t = threadIdx.x;
    int v = (t < nb) ? blocksums[t] : 0;
    sh[t] = v;
    __syncthreads();
    for (int off = 1; off < 512; off <<= 1) {
        int o = (t >= off) ? sh[t - off] : 0;
        __syncthreads();
        sh[t] += o;
        __syncthreads();
    }
    if (t < nb) blockoffs[t] = sh[t] - v;  // exclusive
    if (t == nb - 1) rowptr[n] = sh[t];    // total
}

__global__ void scan3_kernel(const int* __restrict__ counts, const int* __restrict__ blockoffs,
                             int* __restrict__ rowptr, int* __restrict__ woff, int n) {
    __shared__ int sh[SCAN_BLK];
    int t = threadIdx.x;
    int i = blockIdx.x * SCAN_BLK + t;
    int v = (i < n) ? counts[i] : 0;
    sh[t] = v;
    __syncthreads();
    for (int off = 1; off < SCAN_BLK; off <<= 1) {
        int o = (t >= off) ? sh[t - off] : 0;
        __syncthreads();
        sh[t] += o;
        __syncthreads();
    }
    if (i < n) {
        int excl = sh[t] - v + blockoffs[blockIdx.x];
        rowptr[i] = excl;
        woff[i] = excl;
    }
}

__global__ void scatter_kernel(const int* __restrict__ ei, const float* __restrict__ ea,
                               const float* __restrict__ dinv, int* __restrict__ woff,
                               int* __restrict__ ccol, float* __restrict__ cval, int E) {
    int e = blockIdx.x * blockDim.x + threadIdx.x;
    if (e >= E) return;
    int r = ei[e];
    int c = ei[E + e];
    int pos = atomicAdd(&woff[r], 1);
    ccol[pos] = c;
    cval[pos] = dinv[r] * ea[e] * dinv[c];
}

// ---------- scalar recurrence coefficients ----------
__global__ void coef_kernel(const float* __restrict__ alpha_params, float* __restrict__ coefs) {
    if (threadIdx.x != 0 || blockIdx.x != 0) return;
    const float a = 1.0f, b = 1.0f, l = -1.0f, r = 1.0f, basealpha = 1.0f;
    float alphas[DEPTH + 1];
    for (int i = 0; i <= DEPTH; ++i) alphas[i] = basealpha * tanhf(alpha_params[i]);
    float coef1 = (a - b) * 0.5f - (a + b + 2.0f) * 0.5f * (l + r) / (r - l);
    float coef2 = (a + b + 2.0f) / (r - l);
    coefs[3 * 1 + 0] = alphas[0] * coef2;
    coefs[3 * 1 + 1] = alphas[0] * coef1;
    coefs[3 * 1 + 2] = 0.0f;
    for (int L = 2; L <= DEPTH; ++L) {
        float Lf = (float)L;
        float coef_l = 2.0f * Lf * (Lf + a + b) * (2.0f * Lf - 2.0f + a + b);
        float coef_lm1_1 = (2.0f * Lf + a + b - 1.0f) * (2.0f * Lf + a + b) * (2.0f * Lf + a + b - 2.0f);
        float coef_lm1_2 = (2.0f * Lf + a + b - 1.0f) * (a * a - b * b);
        float coef_lm2 = 2.0f * (Lf - 1.0f + a) * (Lf - 1.0f + b) * (2.0f * Lf + a + b);
        float tmp1 = alphas[L - 1] * (coef_lm1_1 / coef_l);
        float tmp2 = alphas[L - 1] * (coef_lm1_2 / coef_l);
        float tmp3 = alphas[L - 1] * alphas[L - 2] * (coef_lm2 / coef_l);
        float tmp1_2 = tmp1 * (2.0f / (r - l));
        float tmp2_2 = tmp1 * ((r + l) / (r - l)) + tmp2;
        coefs[3 * L + 0] = tmp1_2;
        coefs[3 * L + 1] = -tmp2_2;
        coefs[3 * L + 2] = -tmp3;
    }
}

// ---------- xs[0] = x into out[:, 0, :] ----------
__global__ void copyx_kernel(const float* __restrict__ x, float* __restrict__ out, int n) {
    int i = blockIdx.x * blockDim.x + threadIdx.x;
    if (i >= n * DFEAT) return;
    int node = i >> 6;
    int lane = i & 63;
    out[(size_t)node * STRIDE + lane] = x[i];
}

// ---------- fused spmm + recurrence ----------
// One wave per node. Wave reshaped as 4 edge-slots (g) x 16 feature-quads (f):
// each lane gathers a float4, so one dwordx4 instruction covers 4 edges' 256B row
// segment; 2-deep unroll keeps 8 edges in flight. Edge-slot partial sums folded
// by shfl_xor(16/32). Guarded slot loads absorb the tail (no remainder loop).
__global__ void spmm_kernel(const int* __restrict__ rowptr, const int* __restrict__ ccol,
                            const float* __restrict__ cval, const float* __restrict__ coefs,
                            float* __restrict__ out, int n, int L) {
    int gid = blockIdx.x * blockDim.x + threadIdx.x;
    int node = gid >> 6;
    if (node >= n) return;
    int lane = threadIdx.x & 63;
    int g = lane >> 4;   // edge sub-slot 0..3
    int f = lane & 15;   // feature quad 0..15
    int s = rowptr[node];
    int e_end = rowptr[node + 1];
    const float* prev = out + (size_t)(L - 1) * DFEAT;  // xs[L-1]: col*STRIDE + feat

    float4 acc0 = make_float4(0.f, 0.f, 0.f, 0.f);
    float4 acc1 = make_float4(0.f, 0.f, 0.f, 0.f);
    for (int base = s; base < e_end; base += 8) {
        int e0 = base + g;
        int e1 = base + 4 + g;
        bool b0 = e0 < e_end, b1 = e1 < e_end;
        int c0 = b0 ? ccol[e0] : 0;
        float v0 = b0 ? cval[e0] : 0.0f;
        int c1 = b1 ? ccol[e1] : 0;
        float v1 = b1 ? cval[e1] : 0.0f;
        float4 x0 = *((const float4*)(prev + (size_t)c0 * STRIDE) + f);
        float4 x1 = *((const float4*)(prev + (size_t)c1 * STRIDE) + f);
        acc0.x += v0 * x0.x; acc0.y += v0 * x0.y; acc0.z += v0 * x0.z; acc0.w += v0 * x0.w;
        acc1.x += v1 * x1.x; acc1.y += v1 * x1.y; acc1.z += v1 * x1.z; acc1.w += v1 * x1.w;
    }
    float4 acc;
    acc.x = acc0.x + acc1.x; acc.y = acc0.y + acc1.y;
    acc.z = acc0.z + acc1.z; acc.w = acc0.w + acc1.w;
    // fold the 4 edge-slots: lanes {f, f+16, f+32, f+48}
    acc.x += __shfl_xor(acc.x, 16, 64); acc.y += __shfl_xor(acc.y, 16, 64);
    acc.z += __shfl_xor(acc.z, 16, 64); acc.w += __shfl_xor(acc.w, 16, 64);
    acc.x += __shfl_xor(acc.x, 32, 64); acc.y += __shfl_xor(acc.y, 32, 64);
    acc.z += __shfl_xor(acc.z, 32, 64); acc.w += __shfl_xor(acc.w, 32, 64);

    if (g == 0) {
        float cA = coefs[3 * L + 0];
        float cB = coefs[3 * L + 1];
        float cC = coefs[3 * L + 2];
        size_t base = (size_t)node * STRIDE;
        float4 p1 = *((const float4*)(out + base + (size_t)(L - 1) * DFEAT) + f);
        float4 p2 = make_float4(0.f, 0.f, 0.f, 0.f);
        if (L >= 2) p2 = *((const float4*)(out + base + (size_t)(L - 2) * DFEAT) + f);
        float4 r;
        r.x = cA * acc.x + cB * p1.x + cC * p2.x;
        r.y = cA * acc.y + cB * p1.y + cC * p2.y;
        r.z = cA * acc.z + cB * p1.z + cC * p2.z;
        r.w = cA * acc.w + cB * p1.w + cC * p2.w;
        *((float4*)(out + base + (size_t)L * DFEAT) + f) = r;
    }
}

extern "C" void kernel_launch(void* const* d_in, const int* in_sizes, int n_in,
                              void* d_out, int out_size, void* d_ws, size_t ws_size,
                              hipStream_t stream) {
    const float* x = (const float*)d_in[0];
    const float* ea = (const float*)d_in[1];
    const float* alpha = (const float*)d_in[2];
    const int* ei = (const int*)d_in[3];
    float* out = (float*)d_out;
    int n = in_sizes[0] / DFEAT;  // 100000
    int E = in_sizes[1];          // 1600000
    int nb = (n + SCAN_BLK - 1) / SCAN_BLK;  // 391

    char* ws = (char*)d_ws;
    size_t off = 0;
    auto alloc = [&](size_t bytes) -> void* {
        void* p = ws + off;
        off += (bytes + 255) & ~(size_t)255;
        return p;
    };
    int* counts = (int*)alloc((size_t)n * 4);
    int* rowptr = (int*)alloc((size_t)(n + 1) * 4);
    int* woff = (int*)alloc((size_t)n * 4);
    float* dinv = (float*)alloc((size_t)n * 4);
    int* ccol = (int*)alloc((size_t)E * 4);
    float* cval = (float*)alloc((size_t)E * 4);
    float* coefs = (float*)alloc(3 * (DEPTH + 1) * 4);
    int* blocksums = (int*)alloc((size_t)nb * 4);
    int* blockoffs = (int*)alloc((size_t)nb * 4);

    hipMemsetAsync(counts, 0, (size_t)n * 4, stream);
    hist_kernel<<<(E + 255) / 256, 256, 0, stream>>>(ei, counts, E);
    dinv_kernel<<<nb, 256, 0, stream>>>(counts, dinv, n);
    scan1_kernel<<<nb, SCAN_BLK, 0, stream>>>(counts, blocksums, n);
    scan2_kernel<<<1, 512, 0, stream>>>(blocksums, blockoffs, rowptr, nb, n);
    scan3_kernel<<<nb, SCAN_BLK, 0, stream>>>(counts, blockoffs, rowptr, woff, n);
    scatter_kernel<<<(E + 255) / 256, 256, 0, stream>>>(ei, ea, dinv, woff, ccol, cval, E);
    coef_kernel<<<1, 64, 0, stream>>>(alpha, coefs);
    copyx_kernel<<<(n * DFEAT + 255) / 256, 256, 0, stream>>>(x, out, n);

    int spmm_blocks = (int)(((size_t)n * 64 + 255) / 256);
    for (int L = 1; L <= DEPTH; ++L) {
        spmm_kernel<<<spmm_blocks, 256, 0, stream>>>(rowptr, ccol, cval, coefs, out, n, L);
    }
}

// Round 5
// 852.334 us; speedup vs baseline: 2.2805x; 1.0413x over previous
//
#include <hip/hip_runtime.h>

#define NNODE 100000
#define NEDGE 1600000
#define DFEAT 64
#define DEPTH 10
#define STRIDE ((DEPTH + 1) * DFEAT)  // 704 floats per node in output
#define SCAN_BLK 256

typedef float float4v __attribute__((ext_vector_type(4)));

// ---------- CSR build ----------

__global__ void hist_kernel(const int* __restrict__ ei, int* __restrict__ counts, int E) {
    int e = blockIdx.x * blockDim.x + threadIdx.x;
    if (e < E) atomicAdd(&counts[ei[e]], 1);
}

// Hierarchical scan: (1) per-block sums, (2) scan block sums (1 block), (3) per-block scan + offset.
__global__ void scan1_kernel(const int* __restrict__ counts, int* __restrict__ blocksums, int n) {
    __shared__ int sh[SCAN_BLK];
    int t = threadIdx.x;
    int i = blockIdx.x * SCAN_BLK + t;
    sh[t] = (i < n) ? counts[i] : 0;
    __syncthreads();
    for (int off = SCAN_BLK / 2; off > 0; off >>= 1) {
        if (t < off) sh[t] += sh[t + off];
        __syncthreads();
    }
    if (t == 0) blocksums[blockIdx.x] = sh[0];
}

__global__ void scan2_kernel(const int* __restrict__ blocksums, int* __restrict__ blockoffs,
                             int* __restrict__ rowptr, int nb, int n) {
    __shared__ int sh[512];
    int t = threadIdx.x;
    int v = (t < nb) ? blocksums[t] : 0;
    sh[t] = v;
    __syncthreads();
    for (int off = 1; off < 512; off <<= 1) {
        int o = (t >= off) ? sh[t - off] : 0;
        __syncthreads();
        sh[t] += o;
        __syncthreads();
    }
    if (t < nb) blockoffs[t] = sh[t] - v;  // exclusive
    if (t == nb - 1) rowptr[n] = sh[t];    // total
}

// Per-block exclusive scan + offset; also emits dinv.
__global__ void scan3_kernel(const int* __restrict__ counts, const int* __restrict__ blockoffs,
                             int* __restrict__ rowptr, int* __restrict__ woff,
                             float* __restrict__ dinv, int n) {
    __shared__ int sh[SCAN_BLK];
    int t = threadIdx.x;
    int i = blockIdx.x * SCAN_BLK + t;
    int v = (i < n) ? counts[i] : 0;
    sh[t] = v;
    __syncthreads();
    for (int off = 1; off < SCAN_BLK; off <<= 1) {
        int o = (t >= off) ? sh[t - off] : 0;
        __syncthreads();
        sh[t] += o;
        __syncthreads();
    }
    if (i < n) {
        int excl = sh[t] - v + blockoffs[blockIdx.x];
        rowptr[i] = excl;
        woff[i] = excl;
        float d = (float)v;
        if (d < 0.5f) d += 1.0f;  // reference: deg<0.5 -> deg+1
        dinv[i] = rsqrtf(d);
    }
}

__global__ void scatter_kernel(const int* __restrict__ ei, const float* __restrict__ ea,
                               const float* __restrict__ dinv, int* __restrict__ woff,
                               int2* __restrict__ cvpack, int E) {
    int e = blockIdx.x * blockDim.x + threadIdx.x;
    if (e >= E) return;
    int r = ei[e];
    int c = ei[E + e];
    int pos = atomicAdd(&woff[r], 1);
    float v = dinv[r] * ea[e] * dinv[c];
    cvpack[pos] = make_int2(c, __float_as_int(v));
}

// ---------- scalar recurrence coefficients ----------
__global__ void coef_kernel(const float* __restrict__ alpha_params, float* __restrict__ coefs) {
    if (threadIdx.x != 0 || blockIdx.x != 0) return;
    const float a = 1.0f, b = 1.0f, l = -1.0f, r = 1.0f, basealpha = 1.0f;
    float alphas[DEPTH + 1];
    for (int i = 0; i <= DEPTH; ++i) alphas[i] = basealpha * tanhf(alpha_params[i]);
    float coef1 = (a - b) * 0.5f - (a + b + 2.0f) * 0.5f * (l + r) / (r - l);
    float coef2 = (a + b + 2.0f) / (r - l);
    coefs[3 * 1 + 0] = alphas[0] * coef2;
    coefs[3 * 1 + 1] = alphas[0] * coef1;
    coefs[3 * 1 + 2] = 0.0f;
    for (int L = 2; L <= DEPTH; ++L) {
        float Lf = (float)L;
        float coef_l = 2.0f * Lf * (Lf + a + b) * (2.0f * Lf - 2.0f + a + b);
        float coef_lm1_1 = (2.0f * Lf + a + b - 1.0f) * (2.0f * Lf + a + b) * (2.0f * Lf + a + b - 2.0f);
        float coef_lm1_2 = (2.0f * Lf + a + b - 1.0f) * (a * a - b * b);
        float coef_lm2 = 2.0f * (Lf - 1.0f + a) * (Lf - 1.0f + b) * (2.0f * Lf + a + b);
        float tmp1 = alphas[L - 1] * (coef_lm1_1 / coef_l);
        float tmp2 = alphas[L - 1] * (coef_lm1_2 / coef_l);
        float tmp3 = alphas[L - 1] * alphas[L - 2] * (coef_lm2 / coef_l);
        float tmp1_2 = tmp1 * (2.0f / (r - l));
        float tmp2_2 = tmp1 * ((r + l) / (r - l)) + tmp2;
        coefs[3 * L + 0] = tmp1_2;
        coefs[3 * L + 1] = -tmp2_2;
        coefs[3 * L + 2] = -tmp3;
    }
}

// ---------- xs[0] = x into out[:, 0, :] (nontemporal: write-once, never re-read) ----------
__global__ void copyx_kernel(const float* __restrict__ x, float* __restrict__ out, int n) {
    int i = blockIdx.x * blockDim.x + threadIdx.x;  // quad index
    if (i >= n * 16) return;
    int node = i >> 4;
    int q = i & 15;
    float4v v = ((const float4v*)x)[i];
    __builtin_nontemporal_store(v, (float4v*)(out + (size_t)node * STRIDE) + q);
}

// ---------- fused spmm + recurrence ----------
// One wave per node, 4 edge-slots (g) x 16 feature-quads (f). Gathers come from a
// compact [N,64] buffer (gsrc) that stays L3/L2-hot; out is written nontemporally
// (write-once) so it never evicts the gather working set. cur = compact copy of
// this level for the next level's gather.
__global__ void spmm_kernel(const int* __restrict__ rowptr, const int2* __restrict__ cvpack,
                            const float* __restrict__ coefs,
                            const float* __restrict__ gsrc,   // x_{L-1} compact [N,64]
                            const float* __restrict__ p2src,  // x_{L-2} compact (any valid ptr for L=1; cC=0)
                            float* __restrict__ cur,          // x_L compact out
                            float* __restrict__ out, int n, int L) {
    int gid = blockIdx.x * blockDim.x + threadIdx.x;
    int node = gid >> 6;
    if (node >= n) return;
    int lane = threadIdx.x & 63;
    int g = lane >> 4;   // edge sub-slot 0..3
    int f = lane & 15;   // feature quad 0..15
    int s = rowptr[node];
    int e_end = rowptr[node + 1];

    float4v acc0 = {0.f, 0.f, 0.f, 0.f};
    float4v acc1 = {0.f, 0.f, 0.f, 0.f};
    for (int base = s; base < e_end; base += 8) {
        int e0 = base + g;
        int e1 = base + 4 + g;
        bool b0 = e0 < e_end, b1 = e1 < e_end;
        int2 p0 = b0 ? cvpack[e0] : make_int2(0, 0);
        int2 p1i = b1 ? cvpack[e1] : make_int2(0, 0);
        float v0 = __int_as_float(p0.y);
        float v1 = __int_as_float(p1i.y);
        float4v x0 = *((const float4v*)(gsrc + (size_t)p0.x * DFEAT) + f);
        float4v x1 = *((const float4v*)(gsrc + (size_t)p1i.x * DFEAT) + f);
        acc0 += v0 * x0;
        acc1 += v1 * x1;
    }
    float4v acc = acc0 + acc1;
    // fold the 4 edge-slots: lanes {f, f+16, f+32, f+48}
    acc.x += __shfl_xor(acc.x, 16, 64); acc.y += __shfl_xor(acc.y, 16, 64);
    acc.z += __shfl_xor(acc.z, 16, 64); acc.w += __shfl_xor(acc.w, 16, 64);
    acc.x += __shfl_xor(acc.x, 32, 64); acc.y += __shfl_xor(acc.y, 32, 64);
    acc.z += __shfl_xor(acc.z, 32, 64); acc.w += __shfl_xor(acc.w, 32, 64);

    if (g == 0) {
        float cA = coefs[3 * L + 0];
        float cB = coefs[3 * L + 1];
        float cC = coefs[3 * L + 2];
        size_t nb = (size_t)node * DFEAT;
        float4v p1 = *((const float4v*)(gsrc + nb) + f);
        float4v p2 = *((const float4v*)(p2src + nb) + f);
        float4v r = cA * acc + cB * p1 + cC * p2;
        ((float4v*)(cur + nb))[f] = r;  // compact copy for next level (cached)
        __builtin_nontemporal_store(r, (float4v*)(out + (size_t)node * STRIDE + (size_t)L * DFEAT) + f);
    }
}

extern "C" void kernel_launch(void* const* d_in, const int* in_sizes, int n_in,
                              void* d_out, int out_size, void* d_ws, size_t ws_size,
                              hipStream_t stream) {
    const float* x = (const float*)d_in[0];
    const float* ea = (const float*)d_in[1];
    const float* alpha = (const float*)d_in[2];
    const int* ei = (const int*)d_in[3];
    float* out = (float*)d_out;
    int n = in_sizes[0] / DFEAT;  // 100000
    int E = in_sizes[1];          // 1600000
    int nb = (n + SCAN_BLK - 1) / SCAN_BLK;  // 391

    char* ws = (char*)d_ws;
    size_t off = 0;
    auto alloc = [&](size_t bytes) -> void* {
        void* p = ws + off;
        off += (bytes + 255) & ~(size_t)255;
        return p;
    };
    int* counts = (int*)alloc((size_t)n * 4);
    int* rowptr = (int*)alloc((size_t)(n + 1) * 4);
    int* woff = (int*)alloc((size_t)n * 4);
    float* dinv = (float*)alloc((size_t)n * 4);
    int2* cvpack = (int2*)alloc((size_t)E * 8);
    float* coefs = (float*)alloc(3 * (DEPTH + 1) * 4);
    int* blocksums = (int*)alloc((size_t)nb * 4);
    int* blockoffs = (int*)alloc((size_t)nb * 4);
    float* xb0 = (float*)alloc((size_t)n * DFEAT * 4);  // compact ping
    float* xb1 = (float*)alloc((size_t)n * DFEAT * 4);  // compact pong

    hipMemsetAsync(counts, 0, (size_t)n * 4, stream);
    hist_kernel<<<(E + 255) / 256, 256, 0, stream>>>(ei, counts, E);
    scan1_kernel<<<nb, SCAN_BLK, 0, stream>>>(counts, blocksums, n);
    scan2_kernel<<<1, 512, 0, stream>>>(blocksums, blockoffs, rowptr, nb, n);
    scan3_kernel<<<nb, SCAN_BLK, 0, stream>>>(counts, blockoffs, rowptr, woff, dinv, n);
    scatter_kernel<<<(E + 255) / 256, 256, 0, stream>>>(ei, ea, dinv, woff, cvpack, E);
    coef_kernel<<<1, 64, 0, stream>>>(alpha, coefs);
    copyx_kernel<<<(n * 16 + 255) / 256, 256, 0, stream>>>(x, out, n);

    int spmm_blocks = (int)(((size_t)n * 64 + 255) / 256);
    // ping-pong: level L gathers gsrc=x_{L-1}, p2src=x_{L-2}, writes cur=x_L
    const float* gsrc = x;
    const float* p2src = x;  // unused at L=1 (cC=0), must be a valid pointer
    float* bufs[2] = {xb0, xb1};
    for (int L = 1; L <= DEPTH; ++L) {
        float* cur = bufs[(L - 1) & 1];
        spmm_kernel<<<spmm_blocks, 256, 0, stream>>>(rowptr, cvpack, coefs, gsrc, p2src, cur, out, n, L);
        p2src = gsrc;
        gsrc = cur;
    }
}

// Round 6
// 732.932 us; speedup vs baseline: 2.6521x; 1.1629x over previous
//
#include <hip/hip_runtime.h>

#define NNODE 100000
#define NEDGE 1600000
#define DFEAT 64
#define DEPTH 10
#define STRIDE ((DEPTH + 1) * DFEAT)  // 704 floats per node in output
#define SCAN_BLK 256

typedef float float4v __attribute__((ext_vector_type(4)));

__device__ inline float bf16_to_f32(unsigned short u) {
    return __uint_as_float(((unsigned int)u) << 16);
}
__device__ inline unsigned short f32_to_bf16_rne(float f) {
    unsigned int u = __float_as_uint(f);
    u += 0x7FFFu + ((u >> 16) & 1u);
    return (unsigned short)(u >> 16);
}

// ---------- CSR build ----------

__global__ void hist_kernel(const int* __restrict__ ei, int* __restrict__ counts, int E) {
    int e = blockIdx.x * blockDim.x + threadIdx.x;
    if (e < E) atomicAdd(&counts[ei[e]], 1);
}

__global__ void scan1_kernel(const int* __restrict__ counts, int* __restrict__ blocksums, int n) {
    __shared__ int sh[SCAN_BLK];
    int t = threadIdx.x;
    int i = blockIdx.x * SCAN_BLK + t;
    sh[t] = (i < n) ? counts[i] : 0;
    __syncthreads();
    for (int off = SCAN_BLK / 2; off > 0; off >>= 1) {
        if (t < off) sh[t] += sh[t + off];
        __syncthreads();
    }
    if (t == 0) blocksums[blockIdx.x] = sh[0];
}

__global__ void scan2_kernel(const int* __restrict__ blocksums, int* __restrict__ blockoffs,
                             int* __restrict__ rowptr, int nb, int n) {
    __shared__ int sh[512];
    int t = threadIdx.x;
    int v = (t < nb) ? blocksums[t] : 0;
    sh[t] = v;
    __syncthreads();
    for (int off = 1; off < 512; off <<= 1) {
        int o = (t >= off) ? sh[t - off] : 0;
        __syncthreads();
        sh[t] += o;
        __syncthreads();
    }
    if (t < nb) blockoffs[t] = sh[t] - v;  // exclusive
    if (t == nb - 1) rowptr[n] = sh[t];    // total
}

__global__ void scan3_kernel(const int* __restrict__ counts, const int* __restrict__ blockoffs,
                             int* __restrict__ rowptr, int* __restrict__ woff,
                             float* __restrict__ dinv, int n) {
    __shared__ int sh[SCAN_BLK];
    int t = threadIdx.x;
    int i = blockIdx.x * SCAN_BLK + t;
    int v = (i < n) ? counts[i] : 0;
    sh[t] = v;
    __syncthreads();
    for (int off = 1; off < SCAN_BLK; off <<= 1) {
        int o = (t >= off) ? sh[t - off] : 0;
        __syncthreads();
        sh[t] += o;
        __syncthreads();
    }
    if (i < n) {
        int excl = sh[t] - v + blockoffs[blockIdx.x];
        rowptr[i] = excl;
        woff[i] = excl;
        float d = (float)v;
        if (d < 0.5f) d += 1.0f;  // reference: deg<0.5 -> deg+1
        dinv[i] = rsqrtf(d);
    }
}

__global__ void scatter_kernel(const int* __restrict__ ei, const float* __restrict__ ea,
                               const float* __restrict__ dinv, int* __restrict__ woff,
                               int2* __restrict__ cvpack, int E) {
    int e = blockIdx.x * blockDim.x + threadIdx.x;
    if (e >= E) return;
    int r = ei[e];
    int c = ei[E + e];
    int pos = atomicAdd(&woff[r], 1);
    float v = dinv[r] * ea[e] * dinv[c];
    cvpack[pos] = make_int2(c, __float_as_int(v));
}

// ---------- scalar recurrence coefficients ----------
__global__ void coef_kernel(const float* __restrict__ alpha_params, float* __restrict__ coefs) {
    if (threadIdx.x != 0 || blockIdx.x != 0) return;
    const float a = 1.0f, b = 1.0f, l = -1.0f, r = 1.0f, basealpha = 1.0f;
    float alphas[DEPTH + 1];
    for (int i = 0; i <= DEPTH; ++i) alphas[i] = basealpha * tanhf(alpha_params[i]);
    float coef1 = (a - b) * 0.5f - (a + b + 2.0f) * 0.5f * (l + r) / (r - l);
    float coef2 = (a + b + 2.0f) / (r - l);
    coefs[3 * 1 + 0] = alphas[0] * coef2;
    coefs[3 * 1 + 1] = alphas[0] * coef1;
    coefs[3 * 1 + 2] = 0.0f;
    for (int L = 2; L <= DEPTH; ++L) {
        float Lf = (float)L;
        float coef_l = 2.0f * Lf * (Lf + a + b) * (2.0f * Lf - 2.0f + a + b);
        float coef_lm1_1 = (2.0f * Lf + a + b - 1.0f) * (2.0f * Lf + a + b) * (2.0f * Lf + a + b - 2.0f);
        float coef_lm1_2 = (2.0f * Lf + a + b - 1.0f) * (a * a - b * b);
        float coef_lm2 = 2.0f * (Lf - 1.0f + a) * (Lf - 1.0f + b) * (2.0f * Lf + a + b);
        float tmp1 = alphas[L - 1] * (coef_lm1_1 / coef_l);
        float tmp2 = alphas[L - 1] * (coef_lm1_2 / coef_l);
        float tmp3 = alphas[L - 1] * alphas[L - 2] * (coef_lm2 / coef_l);
        float tmp1_2 = tmp1 * (2.0f / (r - l));
        float tmp2_2 = tmp1 * ((r + l) / (r - l)) + tmp2;
        coefs[3 * L + 0] = tmp1_2;
        coefs[3 * L + 1] = -tmp2_2;
        coefs[3 * L + 2] = -tmp3;
    }
}

// ---------- level 0: out[:,0,:] = x (NT) and bf16 compact copy ----------
__global__ void copyx_kernel(const float* __restrict__ x, float* __restrict__ out,
                             unsigned short* __restrict__ xb16, int n) {
    int i = blockIdx.x * blockDim.x + threadIdx.x;  // quad index
    if (i >= n * 16) return;
    int node = i >> 4;
    int q = i & 15;
    float4v v = ((const float4v*)x)[i];
    __builtin_nontemporal_store(v, (float4v*)(out + (size_t)node * STRIDE) + q);
    ushort4 b;
    b.x = f32_to_bf16_rne(v.x); b.y = f32_to_bf16_rne(v.y);
    b.z = f32_to_bf16_rne(v.z); b.w = f32_to_bf16_rne(v.w);
    ((ushort4*)xb16)[i] = b;
}

// ---------- fused spmm + recurrence, bf16 gather rows (128B), fp32 accumulate ----------
// One wave per node, 4 edge-slots (g) x 16 lanes (f); each lane loads ushort4 (4 bf16)
// so 16 lanes cover one 128B row. 2-deep unroll = 8 edges in flight.
__global__ void spmm_kernel(const int* __restrict__ rowptr, const int2* __restrict__ cvpack,
                            const float* __restrict__ coefs,
                            const unsigned short* __restrict__ gsrc,   // x_{L-1} bf16 [N,64]
                            const unsigned short* __restrict__ p2src,  // x_{L-2} bf16
                            unsigned short* __restrict__ cur,          // x_L bf16 out
                            float* __restrict__ out, int n, int L) {
    int gid = blockIdx.x * blockDim.x + threadIdx.x;
    int node = gid >> 6;
    if (node >= n) return;
    int lane = threadIdx.x & 63;
    int g = lane >> 4;   // edge sub-slot 0..3
    int f = lane & 15;   // ushort4 index 0..15
    int s = rowptr[node];
    int e_end = rowptr[node + 1];

    float4v acc0 = {0.f, 0.f, 0.f, 0.f};
    float4v acc1 = {0.f, 0.f, 0.f, 0.f};
    for (int base = s; base < e_end; base += 8) {
        int e0 = base + g;
        int e1 = base + 4 + g;
        bool b0 = e0 < e_end, b1 = e1 < e_end;
        int2 p0 = b0 ? cvpack[e0] : make_int2(0, 0);
        int2 p1i = b1 ? cvpack[e1] : make_int2(0, 0);
        float v0 = __int_as_float(p0.y);
        float v1 = __int_as_float(p1i.y);
        ushort4 q0 = ((const ushort4*)(gsrc + (size_t)p0.x * DFEAT))[f];
        ushort4 q1 = ((const ushort4*)(gsrc + (size_t)p1i.x * DFEAT))[f];
        acc0.x += v0 * bf16_to_f32(q0.x); acc0.y += v0 * bf16_to_f32(q0.y);
        acc0.z += v0 * bf16_to_f32(q0.z); acc0.w += v0 * bf16_to_f32(q0.w);
        acc1.x += v1 * bf16_to_f32(q1.x); acc1.y += v1 * bf16_to_f32(q1.y);
        acc1.z += v1 * bf16_to_f32(q1.z); acc1.w += v1 * bf16_to_f32(q1.w);
    }
    float4v acc = acc0 + acc1;
    // fold the 4 edge-slots: lanes {f, f+16, f+32, f+48}
    acc.x += __shfl_xor(acc.x, 16, 64); acc.y += __shfl_xor(acc.y, 16, 64);
    acc.z += __shfl_xor(acc.z, 16, 64); acc.w += __shfl_xor(acc.w, 16, 64);
    acc.x += __shfl_xor(acc.x, 32, 64); acc.y += __shfl_xor(acc.y, 32, 64);
    acc.z += __shfl_xor(acc.z, 32, 64); acc.w += __shfl_xor(acc.w, 32, 64);

    if (g == 0) {
        float cA = coefs[3 * L + 0];
        float cB = coefs[3 * L + 1];
        float cC = coefs[3 * L + 2];
        size_t nb = (size_t)node * DFEAT;
        ushort4 p1b = ((const ushort4*)(gsrc + nb))[f];
        ushort4 p2b = ((const ushort4*)(p2src + nb))[f];
        float4v r;
        r.x = cA * acc.x + cB * bf16_to_f32(p1b.x) + cC * bf16_to_f32(p2b.x);
        r.y = cA * acc.y + cB * bf16_to_f32(p1b.y) + cC * bf16_to_f32(p2b.y);
        r.z = cA * acc.z + cB * bf16_to_f32(p1b.z) + cC * bf16_to_f32(p2b.z);
        r.w = cA * acc.w + cB * bf16_to_f32(p1b.w) + cC * bf16_to_f32(p2b.w);
        ushort4 rb;
        rb.x = f32_to_bf16_rne(r.x); rb.y = f32_to_bf16_rne(r.y);
        rb.z = f32_to_bf16_rne(r.z); rb.w = f32_to_bf16_rne(r.w);
        ((ushort4*)(cur + nb))[f] = rb;  // compact bf16 for next levels
        __builtin_nontemporal_store(r, (float4v*)(out + (size_t)node * STRIDE + (size_t)L * DFEAT) + f);
    }
}

extern "C" void kernel_launch(void* const* d_in, const int* in_sizes, int n_in,
                              void* d_out, int out_size, void* d_ws, size_t ws_size,
                              hipStream_t stream) {
    const float* x = (const float*)d_in[0];
    const float* ea = (const float*)d_in[1];
    const float* alpha = (const float*)d_in[2];
    const int* ei = (const int*)d_in[3];
    float* out = (float*)d_out;
    int n = in_sizes[0] / DFEAT;  // 100000
    int E = in_sizes[1];          // 1600000
    int nb = (n + SCAN_BLK - 1) / SCAN_BLK;  // 391

    char* ws = (char*)d_ws;
    size_t off = 0;
    auto alloc = [&](size_t bytes) -> void* {
        void* p = ws + off;
        off += (bytes + 255) & ~(size_t)255;
        return p;
    };
    int* counts = (int*)alloc((size_t)n * 4);
    int* rowptr = (int*)alloc((size_t)(n + 1) * 4);
    int* woff = (int*)alloc((size_t)n * 4);
    float* dinv = (float*)alloc((size_t)n * 4);
    int2* cvpack = (int2*)alloc((size_t)E * 8);
    float* coefs = (float*)alloc(3 * (DEPTH + 1) * 4);
    int* blocksums = (int*)alloc((size_t)nb * 4);
    int* blockoffs = (int*)alloc((size_t)nb * 4);
    unsigned short* xbA = (unsigned short*)alloc((size_t)n * DFEAT * 2);
    unsigned short* xbB = (unsigned short*)alloc((size_t)n * DFEAT * 2);
    unsigned short* xbC = (unsigned short*)alloc((size_t)n * DFEAT * 2);

    hipMemsetAsync(counts, 0, (size_t)n * 4, stream);
    hist_kernel<<<(E + 255) / 256, 256, 0, stream>>>(ei, counts, E);
    scan1_kernel<<<nb, SCAN_BLK, 0, stream>>>(counts, blocksums, n);
    scan2_kernel<<<1, 512, 0, stream>>>(blocksums, blockoffs, rowptr, nb, n);
    scan3_kernel<<<nb, SCAN_BLK, 0, stream>>>(counts, blockoffs, rowptr, woff, dinv, n);
    scatter_kernel<<<(E + 255) / 256, 256, 0, stream>>>(ei, ea, dinv, woff, cvpack, E);
    coef_kernel<<<1, 64, 0, stream>>>(alpha, coefs);
    copyx_kernel<<<(n * 16 + 255) / 256, 256, 0, stream>>>(x, out, xbA, n);

    int spmm_blocks = (int)(((size_t)n * 64 + 255) / 256);
    // rotate 3 compact buffers: cur, gsrc=x_{L-1}, p2src=x_{L-2} all distinct
    unsigned short* bufs[3] = {xbA, xbB, xbC};
    for (int L = 1; L <= DEPTH; ++L) {
        unsigned short* cur = bufs[L % 3];
        const unsigned short* gsrc = bufs[(L - 1) % 3];
        const unsigned short* p2src = bufs[(L + 1) % 3];  // == (L-2) mod 3; valid ptr at L=1 (cC=0)
        spmm_kernel<<<spmm_blocks, 256, 0, stream>>>(rowptr, cvpack, coefs, gsrc, p2src, cur, out, n, L);
    }
}

// Round 7
// 648.008 us; speedup vs baseline: 2.9996x; 1.1311x over previous
//
#include <hip/hip_runtime.h>

#define NNODE 100000
#define NEDGE 1600000
#define DFEAT 64
#define DEPTH 10
#define STRIDE ((DEPTH + 1) * DFEAT)  // 704 floats per node in output
#define SCAN_BLK 256

typedef float float4v __attribute__((ext_vector_type(4)));
typedef unsigned short ushort8v __attribute__((ext_vector_type(8)));

__device__ inline float bf16_to_f32(unsigned short u) {
    return __uint_as_float(((unsigned int)u) << 16);
}
__device__ inline unsigned short f32_to_bf16_rne(float f) {
    unsigned int u = __float_as_uint(f);
    u += 0x7FFFu + ((u >> 16) & 1u);
    return (unsigned short)(u >> 16);
}

// ---------- CSR build ----------

__global__ void hist_kernel(const int* __restrict__ ei, int* __restrict__ counts, int E) {
    int e = blockIdx.x * blockDim.x + threadIdx.x;
    if (e < E) atomicAdd(&counts[ei[e]], 1);
}

__global__ void scan1_kernel(const int* __restrict__ counts, int* __restrict__ blocksums, int n) {
    __shared__ int sh[SCAN_BLK];
    int t = threadIdx.x;
    int i = blockIdx.x * SCAN_BLK + t;
    sh[t] = (i < n) ? counts[i] : 0;
    __syncthreads();
    for (int off = SCAN_BLK / 2; off > 0; off >>= 1) {
        if (t < off) sh[t] += sh[t + off];
        __syncthreads();
    }
    if (t == 0) blocksums[blockIdx.x] = sh[0];
}

__global__ void scan2_kernel(const int* __restrict__ blocksums, int* __restrict__ blockoffs,
                             int* __restrict__ rowptr, int nb, int n) {
    __shared__ int sh[512];
    int t = threadIdx.x;
    int v = (t < nb) ? blocksums[t] : 0;
    sh[t] = v;
    __syncthreads();
    for (int off = 1; off < 512; off <<= 1) {
        int o = (t >= off) ? sh[t - off] : 0;
        __syncthreads();
        sh[t] += o;
        __syncthreads();
    }
    if (t < nb) blockoffs[t] = sh[t] - v;  // exclusive
    if (t == nb - 1) rowptr[n] = sh[t];    // total
}

__global__ void scan3_kernel(const int* __restrict__ counts, const int* __restrict__ blockoffs,
                             int* __restrict__ rowptr, int* __restrict__ woff,
                             float* __restrict__ dinv, int n) {
    __shared__ int sh[SCAN_BLK];
    int t = threadIdx.x;
    int i = blockIdx.x * SCAN_BLK + t;
    int v = (i < n) ? counts[i] : 0;
    sh[t] = v;
    __syncthreads();
    for (int off = 1; off < SCAN_BLK; off <<= 1) {
        int o = (t >= off) ? sh[t - off] : 0;
        __syncthreads();
        sh[t] += o;
        __syncthreads();
    }
    if (i < n) {
        int excl = sh[t] - v + blockoffs[blockIdx.x];
        rowptr[i] = excl;
        woff[i] = excl;
        float d = (float)v;
        if (d < 0.5f) d += 1.0f;  // reference: deg<0.5 -> deg+1
        dinv[i] = rsqrtf(d);
    }
}

__global__ void scatter_kernel(const int* __restrict__ ei, const float* __restrict__ ea,
                               const float* __restrict__ dinv, int* __restrict__ woff,
                               int2* __restrict__ cvpack, int E) {
    int e = blockIdx.x * blockDim.x + threadIdx.x;
    if (e >= E) return;
    int r = ei[e];
    int c = ei[E + e];
    int pos = atomicAdd(&woff[r], 1);
    float v = dinv[r] * ea[e] * dinv[c];
    cvpack[pos] = make_int2(c, __float_as_int(v));
}

// ---------- scalar recurrence coefficients ----------
__global__ void coef_kernel(const float* __restrict__ alpha_params, float* __restrict__ coefs) {
    if (threadIdx.x != 0 || blockIdx.x != 0) return;
    const float a = 1.0f, b = 1.0f, l = -1.0f, r = 1.0f, basealpha = 1.0f;
    float alphas[DEPTH + 1];
    for (int i = 0; i <= DEPTH; ++i) alphas[i] = basealpha * tanhf(alpha_params[i]);
    float coef1 = (a - b) * 0.5f - (a + b + 2.0f) * 0.5f * (l + r) / (r - l);
    float coef2 = (a + b + 2.0f) / (r - l);
    coefs[3 * 1 + 0] = alphas[0] * coef2;
    coefs[3 * 1 + 1] = alphas[0] * coef1;
    coefs[3 * 1 + 2] = 0.0f;
    for (int L = 2; L <= DEPTH; ++L) {
        float Lf = (float)L;
        float coef_l = 2.0f * Lf * (Lf + a + b) * (2.0f * Lf - 2.0f + a + b);
        float coef_lm1_1 = (2.0f * Lf + a + b - 1.0f) * (2.0f * Lf + a + b) * (2.0f * Lf + a + b - 2.0f);
        float coef_lm1_2 = (2.0f * Lf + a + b - 1.0f) * (a * a - b * b);
        float coef_lm2 = 2.0f * (Lf - 1.0f + a) * (Lf - 1.0f + b) * (2.0f * Lf + a + b);
        float tmp1 = alphas[L - 1] * (coef_lm1_1 / coef_l);
        float tmp2 = alphas[L - 1] * (coef_lm1_2 / coef_l);
        float tmp3 = alphas[L - 1] * alphas[L - 2] * (coef_lm2 / coef_l);
        float tmp1_2 = tmp1 * (2.0f / (r - l));
        float tmp2_2 = tmp1 * ((r + l) / (r - l)) + tmp2;
        coefs[3 * L + 0] = tmp1_2;
        coefs[3 * L + 1] = -tmp2_2;
        coefs[3 * L + 2] = -tmp3;
    }
}

// ---------- level 0: out[:,0,:] = x (NT) and bf16 compact copy ----------
__global__ void copyx_kernel(const float* __restrict__ x, float* __restrict__ out,
                             unsigned short* __restrict__ xb16, int n) {
    int i = blockIdx.x * blockDim.x + threadIdx.x;  // quad index
    if (i >= n * 16) return;
    int node = i >> 4;
    int q = i & 15;
    float4v v = ((const float4v*)x)[i];
    __builtin_nontemporal_store(v, (float4v*)(out + (size_t)node * STRIDE) + q);
    ushort4 b;
    b.x = f32_to_bf16_rne(v.x); b.y = f32_to_bf16_rne(v.y);
    b.z = f32_to_bf16_rne(v.z); b.w = f32_to_bf16_rne(v.w);
    ((ushort4*)xb16)[i] = b;
}

// ---------- fused spmm + recurrence ----------
// One wave per node. 8 edge-slots (g=lane>>3) x 8 lanes/row (f=lane&7); each lane
// loads ushort8 (16B dwordx4), so ONE gather instruction covers 8 edges' 128B rows.
// 2-deep unroll = 16 edges in flight per wave. Fold slots via shfl_xor(8,16,32).
__global__ void spmm_kernel(const int* __restrict__ rowptr, const int2* __restrict__ cvpack,
                            const float* __restrict__ coefs,
                            const unsigned short* __restrict__ gsrc,   // x_{L-1} bf16 [N,64]
                            const unsigned short* __restrict__ p2src,  // x_{L-2} bf16
                            unsigned short* __restrict__ cur,          // x_L bf16 out
                            float* __restrict__ out, int n, int L) {
    int gid = blockIdx.x * blockDim.x + threadIdx.x;
    int node = gid >> 6;
    if (node >= n) return;
    int lane = threadIdx.x & 63;
    int g = lane >> 3;   // edge sub-slot 0..7
    int f = lane & 7;    // ushort8 (16B) index 0..7 within the 128B row
    int s = rowptr[node];
    int e_end = rowptr[node + 1];

    float acc[8];
#pragma unroll
    for (int j = 0; j < 8; ++j) acc[j] = 0.0f;

    for (int base = s; base < e_end; base += 16) {
        int e0 = base + g;
        int e1 = base + 8 + g;
        bool b0 = e0 < e_end, b1 = e1 < e_end;
        int2 p0 = b0 ? cvpack[e0] : make_int2(0, 0);
        int2 p1i = b1 ? cvpack[e1] : make_int2(0, 0);
        float v0 = __int_as_float(p0.y);
        float v1 = __int_as_float(p1i.y);
        ushort8v q0 = ((const ushort8v*)(gsrc + (size_t)p0.x * DFEAT))[f];
        ushort8v q1 = ((const ushort8v*)(gsrc + (size_t)p1i.x * DFEAT))[f];
#pragma unroll
        for (int j = 0; j < 8; ++j) {
            acc[j] += v0 * bf16_to_f32(q0[j]);
            acc[j] += v1 * bf16_to_f32(q1[j]);
        }
    }
    // fold the 8 edge-slots: lanes {f, f+8, ..., f+56}
#pragma unroll
    for (int j = 0; j < 8; ++j) {
        acc[j] += __shfl_xor(acc[j], 8, 64);
        acc[j] += __shfl_xor(acc[j], 16, 64);
        acc[j] += __shfl_xor(acc[j], 32, 64);
    }

    if (g == 0) {
        float cA = coefs[3 * L + 0];
        float cB = coefs[3 * L + 1];
        float cC = coefs[3 * L + 2];
        size_t nb = (size_t)node * DFEAT;
        ushort8v p1b = ((const ushort8v*)(gsrc + nb))[f];
        ushort8v p2b = ((const ushort8v*)(p2src + nb))[f];
        float r[8];
        ushort8v rb;
#pragma unroll
        for (int j = 0; j < 8; ++j) {
            r[j] = cA * acc[j] + cB * bf16_to_f32(p1b[j]) + cC * bf16_to_f32(p2b[j]);
            rb[j] = f32_to_bf16_rne(r[j]);
        }
        ((ushort8v*)(cur + nb))[f] = rb;  // compact bf16 for next levels
        float4v lo = {r[0], r[1], r[2], r[3]};
        float4v hi = {r[4], r[5], r[6], r[7]};
        float4v* obase = (float4v*)(out + (size_t)node * STRIDE + (size_t)L * DFEAT);
        __builtin_nontemporal_store(lo, obase + 2 * f);
        __builtin_nontemporal_store(hi, obase + 2 * f + 1);
    }
}

extern "C" void kernel_launch(void* const* d_in, const int* in_sizes, int n_in,
                              void* d_out, int out_size, void* d_ws, size_t ws_size,
                              hipStream_t stream) {
    const float* x = (const float*)d_in[0];
    const float* ea = (const float*)d_in[1];
    const float* alpha = (const float*)d_in[2];
    const int* ei = (const int*)d_in[3];
    float* out = (float*)d_out;
    int n = in_sizes[0] / DFEAT;  // 100000
    int E = in_sizes[1];          // 1600000
    int nb = (n + SCAN_BLK - 1) / SCAN_BLK;  // 391

    char* ws = (char*)d_ws;
    size_t off = 0;
    auto alloc = [&](size_t bytes) -> void* {
        void* p = ws + off;
        off += (bytes + 255) & ~(size_t)255;
        return p;
    };
    int* counts = (int*)alloc((size_t)n * 4);
    int* rowptr = (int*)alloc((size_t)(n + 1) * 4);
    int* woff = (int*)alloc((size_t)n * 4);
    float* dinv = (float*)alloc((size_t)n * 4);
    int2* cvpack = (int2*)alloc((size_t)E * 8);
    float* coefs = (float*)alloc(3 * (DEPTH + 1) * 4);
    int* blocksums = (int*)alloc((size_t)nb * 4);
    int* blockoffs = (int*)alloc((size_t)nb * 4);
    unsigned short* xbA = (unsigned short*)alloc((size_t)n * DFEAT * 2);
    unsigned short* xbB = (unsigned short*)alloc((size_t)n * DFEAT * 2);
    unsigned short* xbC = (unsigned short*)alloc((size_t)n * DFEAT * 2);

    hipMemsetAsync(counts, 0, (size_t)n * 4, stream);
    hist_kernel<<<(E + 255) / 256, 256, 0, stream>>>(ei, counts, E);
    scan1_kernel<<<nb, SCAN_BLK, 0, stream>>>(counts, blocksums, n);
    scan2_kernel<<<1, 512, 0, stream>>>(blocksums, blockoffs, rowptr, nb, n);
    scan3_kernel<<<nb, SCAN_BLK, 0, stream>>>(counts, blockoffs, rowptr, woff, dinv, n);
    scatter_kernel<<<(E + 255) / 256, 256, 0, stream>>>(ei, ea, dinv, woff, cvpack, E);
    coef_kernel<<<1, 64, 0, stream>>>(alpha, coefs);
    copyx_kernel<<<(n * 16 + 255) / 256, 256, 0, stream>>>(x, out, xbA, n);

    int spmm_blocks = (int)(((size_t)n * 64 + 255) / 256);
    // rotate 3 compact buffers: cur, gsrc=x_{L-1}, p2src=x_{L-2} all distinct
    unsigned short* bufs[3] = {xbA, xbB, xbC};
    for (int L = 1; L <= DEPTH; ++L) {
        unsigned short* cur = bufs[L % 3];
        const unsigned short* gsrc = bufs[(L - 1) % 3];
        const unsigned short* p2src = bufs[(L + 1) % 3];  // == (L-2) mod 3; valid ptr at L=1 (cC=0)
        spmm_kernel<<<spmm_blocks, 256, 0, stream>>>(rowptr, cvpack, coefs, gsrc, p2src, cur, out, n, L);
    }
}